// Round 16
// baseline (103.679 us; speedup 1.0000x reference)
//
#include <hip/hip_runtime.h>
#include <math.h>

#define T_STEPS 22
#define F_IN    12
#define HID     32

typedef __attribute__((ext_vector_type(8))) short  bf16x8;
typedef __attribute__((ext_vector_type(4)))  float f32x4;
typedef __attribute__((ext_vector_type(2)))  float f32x2;

union FragU { unsigned int u[4]; bf16x8 v; };

#define LOG2E    1.442695041f
#define TWOLOG2E 2.885390082f

static __device__ __forceinline__ unsigned short f2bf(float x) {
    unsigned int u = __builtin_bit_cast(unsigned int, x);
    return (unsigned short)((u + 0x7fffu + ((u >> 16) & 1u)) >> 16);
}

static __device__ __forceinline__ unsigned cvt_pk_bf16(float lo, float hi) {
    unsigned r;
    asm("v_cvt_pk_bf16_f32 %0, %1, %2" : "=v"(r) : "v"(lo), "v"(hi));
    return r;
}

// 16x16x32 + chat column permutation (verified r8/r11/r13/r14): zero-shuffle
// h repack. ws layout (floats):
//   [0,2048)    wx16: [8 tile][64 lane] x 8 bf16, rows prescaled; k=12 = fused bias
//   [2048,4096) wh16: [8 tile][64 lane] x 8 bf16, cols chat-permuted, prescaled
//   [4096,4128) whd:  [4 s][8 j] f32; j<4 -> Whead[4s+j], j>=4 -> Whead[16+4s+j-4]
__global__ void prep_kernel(const float* __restrict__ Wih, const float* __restrict__ Whh,
                            const float* __restrict__ bih, const float* __restrict__ bhh,
                            const float* __restrict__ Whead, float* __restrict__ ws) {
    const int tid = threadIdx.x;  // 256
    unsigned short* wx = (unsigned short*)ws;
    unsigned short* wh = (unsigned short*)(ws + 2048);
    float* whd = ws + 4096;

    for (int e = tid; e < 512; e += 256) {
        int tile = e >> 6, lane = e & 63;
        int row = lane & 15, s = lane >> 4;
        int g = 16 * tile + row;
        float scale = (tile == 4 || tile == 5) ? TWOLOG2E : -LOG2E;  // g-gate: +2log2e
        for (int j = 0; j < 8; ++j) {
            int k = 8 * s + j;
            float v = 0.0f;
            if (k < F_IN)       v = Wih[g * F_IN + k];
            else if (k == F_IN) v = bih[g] + bhh[g];
            wx[e * 8 + j] = f2bf(scale * v);
            int cc = (j < 4) ? (4 * s + j) : (16 + 4 * s + (j - 4));  // chat(k)
            wh[e * 8 + j] = f2bf(scale * Whh[g * HID + cc]);
        }
    }
    if (tid < 32) {
        int s = tid >> 3, j = tid & 7;
        int orig = (j < 4) ? (4 * s + j) : (16 + 4 * s + (j - 4));
        whd[tid] = Whead[orig];
    }
}

// r11 structure (16x16, 32 AGPR acc, weights in LDS, fused-rcp cell) with the
// cross-round confound removed:
//  - opaque-zero LICM block (NOT a memory clobber -> x loads pipeline freely)
//  - x prefetched one step ahead (L3 latency hides under previous cell)
//  - no sched_group_barriers (compiler schedules ds_read/MFMA)
// Footprint ~50 VGPR + 36 AGPR -> 5-wave tier.
__global__ void __launch_bounds__(256, 2)
lstm_kernel(const float* __restrict__ x, const float* __restrict__ ws,
            const float* __restrict__ bheadp, float* __restrict__ out, int B) {
    const int tid  = threadIdx.x;
    const int lane = tid & 63;
    const int wave = tid >> 6;
    const int col  = lane & 15;
    const int s    = lane >> 4;
    int b = blockIdx.x * 64 + wave * 16 + col;
    const bool valid = (b < B);
    if (b >= B) b = B - 1;      // clamp; all threads reach barriers

    __shared__ float wlds[4096];    // 16 KB: wx [0,2048), wh [2048,4096)
#pragma unroll
    for (int i = 0; i < 4; ++i)
        ((float4*)wlds)[tid + i * 256] = ((const float4*)ws)[tid + i * 256];
    __syncthreads();

    // x B-frag k-slots: s=0 -> x[0..7]; s=1 -> x[8..11], k12=bias, rest 0;
    // s>=2 -> all zero (their weight cols are zero too).
    const float* xr  = x + (size_t)b * (T_STEPS * F_IN);
    const float* xa  = xr + ((s == 0) ? 0 : 8);
    const float* xbp = xr + ((s == 0) ? 4 : 8);

    f32x2 cc[4], hv[4];   // .x = units 4s+q (even tiles), .y = units 16+4s+q (odd)
#pragma unroll
    for (int q = 0; q < 4; ++q) { cc[q] = (f32x2){0.f, 0.f}; hv[q] = (f32x2){0.f, 0.f}; }
    bf16x8 hf;
#pragma unroll
    for (int j = 0; j < 8; ++j) hf[j] = 0;

    f32x4 zc;   // zero C-in (4 AGPR)
#pragma unroll
    for (int q = 0; q < 4; ++q) zc[q] = 0.0f;

    const f32x2 one2 = {1.0f, 1.0f};

    float4 va = *(const float4*)(xa);
    float4 vb = *(const float4*)(xbp);

#pragma unroll 1
    for (int t = 0; t < T_STEPS; ++t) {
        // opaque zero blocks LICM of weight ds_reads; x loads still pipeline
        int zr = 0;
        asm("" : "+v"(zr));
        const bf16x8* wx_l = ((const bf16x8*)wlds) + zr;          // [8][64]
        const bf16x8* wh_l = ((const bf16x8*)wlds) + 512 + zr;    // [8][64]

        // prefetch next step's x (consumed a full iteration later)
        const int tn = (t + 1 < T_STEPS) ? t + 1 : t;
        float4 na = *(const float4*)(xa  + tn * F_IN);
        float4 nb = *(const float4*)(xbp + tn * F_IN);

        unsigned p0 = cvt_pk_bf16(va.x, va.y);
        unsigned p1 = cvt_pk_bf16(va.z, va.w);
        unsigned p2 = cvt_pk_bf16(vb.x, vb.y);
        unsigned p3 = cvt_pk_bf16(vb.z, vb.w);
        FragU xf;
        if (s == 0)      { xf.u[0] = p0; xf.u[1] = p1; xf.u[2] = p2;          xf.u[3] = p3; }
        else if (s == 1) { xf.u[0] = p0; xf.u[1] = p1; xf.u[2] = 0x00003f80u; xf.u[3] = 0;  }
        else             { xf.u[0] = 0;  xf.u[1] = 0;  xf.u[2] = 0;           xf.u[3] = 0;  }

        f32x4 a0, a1, a2, a3, a4, a5, a6, a7;
        a0 = __builtin_amdgcn_mfma_f32_16x16x32_bf16(wx_l[0 * 64 + lane], xf.v, zc, 0, 0, 0);
        a1 = __builtin_amdgcn_mfma_f32_16x16x32_bf16(wx_l[1 * 64 + lane], xf.v, zc, 0, 0, 0);
        a2 = __builtin_amdgcn_mfma_f32_16x16x32_bf16(wx_l[2 * 64 + lane], xf.v, zc, 0, 0, 0);
        a3 = __builtin_amdgcn_mfma_f32_16x16x32_bf16(wx_l[3 * 64 + lane], xf.v, zc, 0, 0, 0);
        a4 = __builtin_amdgcn_mfma_f32_16x16x32_bf16(wx_l[4 * 64 + lane], xf.v, zc, 0, 0, 0);
        a5 = __builtin_amdgcn_mfma_f32_16x16x32_bf16(wx_l[5 * 64 + lane], xf.v, zc, 0, 0, 0);
        a6 = __builtin_amdgcn_mfma_f32_16x16x32_bf16(wx_l[6 * 64 + lane], xf.v, zc, 0, 0, 0);
        a7 = __builtin_amdgcn_mfma_f32_16x16x32_bf16(wx_l[7 * 64 + lane], xf.v, zc, 0, 0, 0);
        a0 = __builtin_amdgcn_mfma_f32_16x16x32_bf16(wh_l[0 * 64 + lane], hf, a0, 0, 0, 0);
        a1 = __builtin_amdgcn_mfma_f32_16x16x32_bf16(wh_l[1 * 64 + lane], hf, a1, 0, 0, 0);
        a2 = __builtin_amdgcn_mfma_f32_16x16x32_bf16(wh_l[2 * 64 + lane], hf, a2, 0, 0, 0);
        a3 = __builtin_amdgcn_mfma_f32_16x16x32_bf16(wh_l[3 * 64 + lane], hf, a3, 0, 0, 0);
        a4 = __builtin_amdgcn_mfma_f32_16x16x32_bf16(wh_l[4 * 64 + lane], hf, a4, 0, 0, 0);
        a5 = __builtin_amdgcn_mfma_f32_16x16x32_bf16(wh_l[5 * 64 + lane], hf, a5, 0, 0, 0);
        a6 = __builtin_amdgcn_mfma_f32_16x16x32_bf16(wh_l[6 * 64 + lane], hf, a6, 0, 0, 0);
        a7 = __builtin_amdgcn_mfma_f32_16x16x32_bf16(wh_l[7 * 64 + lane], hf, a7, 0, 0, 0);

        // Fused-rcp cell (7 trans/unit), f32x2-packed across the two halves:
        //   A = (1+ei)(1+eg), F = (1+ef)
        //   c' = [2L*(eg-1)*F + c'*A] * rcp(F*A)
        //   h  = (ec-1) * rcp((1+eo)(1+ec)),  ec = exp2(c')
#pragma unroll
        for (int q = 0; q < 4; ++q) {
            f32x2 ei = {__builtin_amdgcn_exp2f(a0[q]), __builtin_amdgcn_exp2f(a1[q])};
            f32x2 ef = {__builtin_amdgcn_exp2f(a2[q]), __builtin_amdgcn_exp2f(a3[q])};
            f32x2 eg = {__builtin_amdgcn_exp2f(a4[q]), __builtin_amdgcn_exp2f(a5[q])};
            f32x2 eo = {__builtin_amdgcn_exp2f(a6[q]), __builtin_amdgcn_exp2f(a7[q])};
            f32x2 A  = (one2 + ei) * (one2 + eg);
            f32x2 F  = one2 + ef;
            f32x2 FA = F * A;
            f32x2 r1 = {__builtin_amdgcn_rcpf(FA.x), __builtin_amdgcn_rcpf(FA.y)};
            f32x2 t2 = eg * (f32x2){TWOLOG2E, TWOLOG2E} - (f32x2){TWOLOG2E, TWOLOG2E};
            f32x2 num = t2 * F + cc[q] * A;
            cc[q] = num * r1;
            f32x2 ec = {__builtin_amdgcn_exp2f(cc[q].x), __builtin_amdgcn_exp2f(cc[q].y)};
            f32x2 r2in = (one2 + eo) * (one2 + ec);
            f32x2 r2 = {__builtin_amdgcn_rcpf(r2in.x), __builtin_amdgcn_rcpf(r2in.y)};
            hv[q] = (ec - one2) * r2;
        }

        // zero-shuffle repack (chat): k-slots j<4 from .x halves, j>=4 from .y
        FragU hh;
        hh.u[0] = cvt_pk_bf16(hv[0].x, hv[1].x);
        hh.u[1] = cvt_pk_bf16(hv[2].x, hv[3].x);
        hh.u[2] = cvt_pk_bf16(hv[0].y, hv[1].y);
        hh.u[3] = cvt_pk_bf16(hv[2].y, hv[3].y);
        hf = hh.v;

        va = na; vb = nb;
    }

    // head: y = h . Whead + bhead ; softplus. Reduce over the 4 s-groups.
    const float* whd = ws + 4096 + s * 8;
    float y = 0.0f;
#pragma unroll
    for (int j = 0; j < 4; ++j) {
        y = fmaf(hv[j].x, whd[j],     y);
        y = fmaf(hv[j].y, whd[4 + j], y);
    }
    y += __shfl_xor(y, 16, 64);
    y += __shfl_xor(y, 32, 64);
    y += bheadp[0];
    float sp = fmaxf(y, 0.0f) + log1pf(expf(-fabsf(y)));
    if (valid && s == 0) out[b] = sp;
}

extern "C" void kernel_launch(void* const* d_in, const int* in_sizes, int n_in,
                              void* d_out, int out_size, void* d_ws, size_t ws_size,
                              hipStream_t stream) {
    const float* x     = (const float*)d_in[0];
    const float* Wih   = (const float*)d_in[1];
    const float* Whh   = (const float*)d_in[2];
    const float* bih   = (const float*)d_in[3];
    const float* bhh   = (const float*)d_in[4];
    const float* Whead = (const float*)d_in[5];
    const float* bhead = (const float*)d_in[6];
    float* out = (float*)d_out;
    float* ws  = (float*)d_ws;

    const int B = in_sizes[0] / (T_STEPS * F_IN);
    const int blocks = (B + 63) / 64;

    hipLaunchKernelGGL(prep_kernel, dim3(1), dim3(256), 0, stream,
                       Wih, Whh, bih, bhh, Whead, ws);
    hipLaunchKernelGGL(lstm_kernel, dim3(blocks), dim3(256), 0, stream,
                       x, ws, bhead, out, B);
}

// Round 17
// 85.467 us; speedup vs baseline: 1.2131x; 1.2131x over previous
//
#include <hip/hip_runtime.h>
#include <math.h>

#define T_STEPS 22
#define F_IN    12
#define HID     32

typedef __attribute__((ext_vector_type(8))) short  bf16x8;
typedef __attribute__((ext_vector_type(16))) float f32x16;
typedef __attribute__((ext_vector_type(2)))  float f32x2;

union FragU { unsigned int u[4]; bf16x8 v; };

#define LOG2E    1.442695041f
#define TWOLOG2E 2.885390082f

static __device__ __forceinline__ unsigned short f2bf(float x) {
    unsigned int u = __builtin_bit_cast(unsigned int, x);
    return (unsigned short)((u + 0x7fffu + ((u >> 16) & 1u)) >> 16);
}

static __device__ __forceinline__ unsigned cvt_pk_bf16(float lo, float hi) {
    unsigned r;
    asm("v_cvt_pk_bf16_f32 %0, %1, %2" : "=v"(r) : "v"(lo), "v"(hi));
    return r;
}

// ws layout (floats):
//   [0,1024)    wx_frag: [4 m][64 lane] x 8 bf16, rows prescaled; k=12 = fused bias
//   [1024,3072) wh_frag: [4 m][2 kt][64 lane] x 8 bf16, rows prescaled
//   [3072,3104) whead:   [2 hi][16 q] f32 permuted to C-layout rows
__global__ void prep_kernel(const float* __restrict__ Wih, const float* __restrict__ Whh,
                            const float* __restrict__ bih, const float* __restrict__ bhh,
                            const float* __restrict__ Whead, float* __restrict__ ws) {
    const int tid = threadIdx.x;  // 256
    unsigned short* wx = (unsigned short*)ws;
    unsigned short* wh = (unsigned short*)(ws + 1024);
    float* whd = ws + 3072;

    {   // wx: entry = m*64 + lane (== tid)
        int m = tid >> 6, lane = tid & 63;
        int g = 32 * m + (lane & 31);
        float scale = (m == 2) ? TWOLOG2E : -LOG2E;   // g-gate: +2log2e; i,f,o: -log2e
        int kbase = 8 * (lane >> 5);
        for (int j = 0; j < 8; ++j) {
            int k = kbase + j;
            float v = 0.0f;
            if (k < F_IN)       v = Wih[g * F_IN + k];
            else if (k == F_IN) v = bih[g] + bhh[g];
            wx[tid * 8 + j] = f2bf(scale * v);
        }
    }
    for (int e = tid; e < 4 * 2 * 64; e += 256) {
        int m = e >> 7, kt = (e >> 6) & 1, lane = e & 63;
        int g = 32 * m + (lane & 31);
        float scale = (m == 2) ? TWOLOG2E : -LOG2E;
        int kbase = 16 * kt + 8 * (lane >> 5);
        for (int j = 0; j < 8; ++j)
            wh[e * 8 + j] = f2bf(scale * Whh[g * HID + kbase + j]);
    }
    if (tid < 32) {
        int hi = tid >> 4, q = tid & 15;
        int j = (q & 3) + 8 * (q >> 2) + 4 * hi;
        whd[tid] = Whead[j];
    }
}

// r10 stream (best: 85.5us) + zc hoist (kills 64 acc-zero writes/step) +
// 1-step x prefetch (hides L2/L3 load latency under previous cell).
// ~104 VGPR + 80 AGPR = 184: same 2-wave tier as r10 (129-256), regs are free.
__global__ void __launch_bounds__(256, 2)
lstm_kernel(const float* __restrict__ x, const float* __restrict__ ws,
            const float* __restrict__ bheadp, float* __restrict__ out, int B) {
    const int lane = threadIdx.x & 63;
    const int wave = threadIdx.x >> 6;
    const int col  = lane & 31;
    const int hi   = lane >> 5;
    int b = blockIdx.x * 128 + wave * 32 + col;
    const bool valid = (b < B);
    if (b >= B) b = B - 1;

    const bf16x8* wxp = (const bf16x8*)ws;
    const bf16x8* whp = (const bf16x8*)(ws + 1024);
    bf16x8 wxf[4], whf[4][2];
#pragma unroll
    for (int m = 0; m < 4; ++m) wxf[m] = wxp[m * 64 + lane];
#pragma unroll
    for (int m = 0; m < 4; ++m)
#pragma unroll
        for (int kt = 0; kt < 2; ++kt) whf[m][kt] = whp[(m * 2 + kt) * 64 + lane];

    // lo lanes read x[0..3],x[4..7]; hi lanes read x[8..11] (2nd load unused there)
    const float* xb1 = x + (size_t)b * (T_STEPS * F_IN) + (hi ? 8 : 0);
    const float* xb2 = x + (size_t)b * (T_STEPS * F_IN) + (hi ? 8 : 4);

    f32x2 c2[8], hv2[8];
#pragma unroll
    for (int p = 0; p < 8; ++p) { c2[p] = (f32x2){0.f, 0.f}; hv2[p] = (f32x2){0.f, 0.f}; }
    bf16x8 hf0, hf1;
#pragma unroll
    for (int j = 0; j < 8; ++j) { hf0[j] = 0; hf1[j] = 0; }

    f32x16 zc;   // hoisted zero C-in: removes 64 acc-zero writes per step
#pragma unroll
    for (int q = 0; q < 16; ++q) zc[q] = 0.0f;

    const f32x2 one2 = {1.0f, 1.0f};

    float4 va = *(const float4*)(xb1);
    float4 vb = *(const float4*)(xb2);

    for (int t = 0; t < T_STEPS; ++t) {
        // prefetch next step's x (consumed a full iteration later; clamp tail)
        const int tn = (t + 1 < T_STEPS) ? t + 1 : t;
        float4 na = *(const float4*)(xb1 + tn * F_IN);
        float4 nb = *(const float4*)(xb2 + tn * F_IN);

        FragU xf;
        xf.u[0] = cvt_pk_bf16(va.x, va.y);
        xf.u[1] = cvt_pk_bf16(va.z, va.w);
        unsigned w2 = cvt_pk_bf16(vb.x, vb.y);
        unsigned w3 = cvt_pk_bf16(vb.z, vb.w);
        xf.u[2] = hi ? 0x00003f80u : w2;   // k=12 -> 1.0 (fused bias feature)
        xf.u[3] = hi ? 0u : w3;

        f32x16 a0, a1, a2, a3;
        a0 = __builtin_amdgcn_mfma_f32_32x32x16_bf16(wxf[0], xf.v, zc, 0, 0, 0);
        a1 = __builtin_amdgcn_mfma_f32_32x32x16_bf16(wxf[1], xf.v, zc, 0, 0, 0);
        a2 = __builtin_amdgcn_mfma_f32_32x32x16_bf16(wxf[2], xf.v, zc, 0, 0, 0);
        a3 = __builtin_amdgcn_mfma_f32_32x32x16_bf16(wxf[3], xf.v, zc, 0, 0, 0);
        a0 = __builtin_amdgcn_mfma_f32_32x32x16_bf16(whf[0][0], hf0, a0, 0, 0, 0);
        a1 = __builtin_amdgcn_mfma_f32_32x32x16_bf16(whf[1][0], hf0, a1, 0, 0, 0);
        a2 = __builtin_amdgcn_mfma_f32_32x32x16_bf16(whf[2][0], hf0, a2, 0, 0, 0);
        a3 = __builtin_amdgcn_mfma_f32_32x32x16_bf16(whf[3][0], hf0, a3, 0, 0, 0);
        a0 = __builtin_amdgcn_mfma_f32_32x32x16_bf16(whf[0][1], hf1, a0, 0, 0, 0);
        a1 = __builtin_amdgcn_mfma_f32_32x32x16_bf16(whf[1][1], hf1, a1, 0, 0, 0);
        a2 = __builtin_amdgcn_mfma_f32_32x32x16_bf16(whf[2][1], hf1, a2, 0, 0, 0);
        a3 = __builtin_amdgcn_mfma_f32_32x32x16_bf16(whf[3][1], hf1, a3, 0, 0, 0);

        // Fused-rcp cell, f32x2-packed full-rate math, scalar trans (7/unit).
        #pragma unroll
        for (int p = 0; p < 8; ++p) {
            const int q0 = 2 * p, q1 = 2 * p + 1;
            f32x2 ei = {__builtin_amdgcn_exp2f(a0[q0]), __builtin_amdgcn_exp2f(a0[q1])};
            f32x2 ef = {__builtin_amdgcn_exp2f(a1[q0]), __builtin_amdgcn_exp2f(a1[q1])};
            f32x2 eg = {__builtin_amdgcn_exp2f(a2[q0]), __builtin_amdgcn_exp2f(a2[q1])};
            f32x2 eo = {__builtin_amdgcn_exp2f(a3[q0]), __builtin_amdgcn_exp2f(a3[q1])};
            f32x2 A  = (one2 + ei) * (one2 + eg);
            f32x2 F  = one2 + ef;
            f32x2 FA = F * A;
            f32x2 r1 = {__builtin_amdgcn_rcpf(FA.x), __builtin_amdgcn_rcpf(FA.y)};
            f32x2 t2 = eg * (f32x2){TWOLOG2E, TWOLOG2E} - (f32x2){TWOLOG2E, TWOLOG2E};
            f32x2 num = t2 * F + c2[p] * A;
            c2[p] = num * r1;
            f32x2 ec = {__builtin_amdgcn_exp2f(c2[p].x), __builtin_amdgcn_exp2f(c2[p].y)};
            f32x2 r2in = (one2 + eo) * (one2 + ec);
            f32x2 r2 = {__builtin_amdgcn_rcpf(r2in.x), __builtin_amdgcn_rcpf(r2in.y)};
            hv2[p] = (ec - one2) * r2;
        }

        // repack h (C-layout) -> next B-fragments
        unsigned P0 = cvt_pk_bf16(hv2[0].x, hv2[0].y);
        unsigned P1 = cvt_pk_bf16(hv2[1].x, hv2[1].y);
        unsigned P2 = cvt_pk_bf16(hv2[2].x, hv2[2].y);
        unsigned P3 = cvt_pk_bf16(hv2[3].x, hv2[3].y);
        unsigned P4 = cvt_pk_bf16(hv2[4].x, hv2[4].y);
        unsigned P5 = cvt_pk_bf16(hv2[5].x, hv2[5].y);
        unsigned P6 = cvt_pk_bf16(hv2[6].x, hv2[6].y);
        unsigned P7 = cvt_pk_bf16(hv2[7].x, hv2[7].y);
        asm("v_permlane32_swap_b32 %0, %1" : "+v"(P0), "+v"(P2));
        asm("v_permlane32_swap_b32 %0, %1" : "+v"(P1), "+v"(P3));
        asm("v_permlane32_swap_b32 %0, %1" : "+v"(P4), "+v"(P6));
        asm("v_permlane32_swap_b32 %0, %1" : "+v"(P5), "+v"(P7));
        FragU h0; h0.u[0] = P0; h0.u[1] = P1; h0.u[2] = P2; h0.u[3] = P3;
        FragU h1; h1.u[0] = P4; h1.u[1] = P5; h1.u[2] = P6; h1.u[3] = P7;
        hf0 = h0.v;
        hf1 = h1.v;

        va = na; vb = nb;
    }

    // head: y = h . Whead + bhead ; softplus
    const float* whd = ws + 3072 + hi * 16;
    float y = 0.0f;
#pragma unroll
    for (int p = 0; p < 8; ++p) {
        y = fmaf(hv2[p].x, whd[2 * p],     y);
        y = fmaf(hv2[p].y, whd[2 * p + 1], y);
    }
    y += __shfl_xor(y, 32, 64);
    y += bheadp[0];
    float sp = fmaxf(y, 0.0f) + log1pf(expf(-fabsf(y)));
    if (valid && hi == 0) out[b] = sp;
}

extern "C" void kernel_launch(void* const* d_in, const int* in_sizes, int n_in,
                              void* d_out, int out_size, void* d_ws, size_t ws_size,
                              hipStream_t stream) {
    const float* x     = (const float*)d_in[0];
    const float* Wih   = (const float*)d_in[1];
    const float* Whh   = (const float*)d_in[2];
    const float* bih   = (const float*)d_in[3];
    const float* bhh   = (const float*)d_in[4];
    const float* Whead = (const float*)d_in[5];
    const float* bhead = (const float*)d_in[6];
    float* out = (float*)d_out;
    float* ws  = (float*)d_ws;

    const int B = in_sizes[0] / (T_STEPS * F_IN);
    const int blocks = (B + 127) / 128;

    hipLaunchKernelGGL(prep_kernel, dim3(1), dim3(256), 0, stream,
                       Wih, Whh, bih, bhh, Whead, ws);
    hipLaunchKernelGGL(lstm_kernel, dim3(blocks), dim3(256), 0, stream,
                       x, ws, bhead, out, B);
}